// Round 3
// baseline (719.568 us; speedup 1.0000x reference)
//
#include <hip/hip_runtime.h>

// MessagePassing: 10 iterations of 3x3 per-pixel-weighted smoothing, fully fused.
//   input [8,64,128,128] f32, weight [8,9,128,128] f32 -> out [8,64,128,128] f32
// R3: full-width tiles (128W x 16H core, 36-row region, halo 10), permuted LDS
// layout (J' = rot7(J)) for conflict-free ds_read_b128, 256 blocks = 1/CU.
// Per thread: 8 px in one region row, 72 weight regs, 4 channels/chunk as float4.

#define NB    8
#define CC    64
#define HH    128
#define WW    128
#define TAPS  9
#define PLANE (HH * WW)

#define TH     16            // output tile rows
#define HALO   10
#define RROWS  36            // TH + 2*HALO
#define RSTR4  129           // LDS row stride in float4 (128 + 1 -> +1 bank-group/row)
#define NTH    576           // 36 rows * 16 strips, 9 waves
#define NSTEPS 10
#define CGRP   16            // channels per block
#define CSUB   4             // channels per chunk (float4)

#define PERM(J) ((((J) & 7) << 4) | ((J) >> 3))   // bijective on 0..127

__device__ __forceinline__ float4 fma4(const float4 a, const float s, const float4 c) {
    return make_float4(fmaf(a.x, s, c.x), fmaf(a.y, s, c.y),
                       fmaf(a.z, s, c.z), fmaf(a.w, s, c.w));
}

__global__ __launch_bounds__(256) void mp_norm_kernel(const float* __restrict__ w,
                                                      float* __restrict__ nw) {
    int tid = blockIdx.x * 256 + threadIdx.x;       // 32768 threads
    int wg = tid & 31;
    int h  = (tid >> 5) & 127;
    int n  = tid >> 12;
    int base = n * TAPS * PLANE + h * WW + wg * 4;
    float4 t[TAPS];
    float sx = 1e-5f, sy = 1e-5f, sz = 1e-5f, sw = 1e-5f;
#pragma unroll
    for (int k = 0; k < TAPS; ++k) {
        t[k] = *reinterpret_cast<const float4*>(w + base + k * PLANE);
        sx += t[k].x; sy += t[k].y; sz += t[k].z; sw += t[k].w;
    }
    float rx = 1.0f / sx, ry = 1.0f / sy, rz = 1.0f / sz, rw = 1.0f / sw;
#pragma unroll
    for (int k = 0; k < TAPS; ++k) {
        float4 o = make_float4(t[k].x * rx, t[k].y * ry, t[k].z * rz, t[k].w * rw);
        *reinterpret_cast<float4*>(nw + base + k * PLANE) = o;
    }
}

__global__ __launch_bounds__(NTH, 1) void mp_fused_kernel(const float* __restrict__ src,
                                                          float* __restrict__ dst,
                                                          const float* __restrict__ nw) {
    __shared__ float4 bufA[RROWS * RSTR4];   // 74,304 B
    __shared__ float4 bufB[RROWS * RSTR4];   // total 148,608 B

    const int bid = blockIdx.x;              // 256 blocks: n*32 + ht*4 + cg
    const int n   = bid >> 5;
    const int ht  = (bid >> 2) & 7;
    const int cg  = bid & 3;
    const int tr0 = ht * TH;
    const int cb  = cg * CGRP;

    const int t   = threadIdx.x;
    const int row = t >> 4;                  // 0..35 region row
    const int s   = t & 15;                  // strip: pixels 8s..8s+7

    // ---- per-thread weights: 8 px x 9 taps in registers for the whole kernel ----
    float wt[TAPS][8];
    {
        const int gr   = tr0 - HALO + row;
        const bool rin = (gr >= 0 && gr < HH);
        const float* nwb = nw + (size_t)n * TAPS * PLANE + (rin ? gr * WW : 0) + s * 8;
#pragma unroll
        for (int k = 0; k < TAPS; ++k)
#pragma unroll
            for (int i = 0; i < 8; ++i)
                wt[k][i] = rin ? nwb[k * PLANE + i] : 0.f;  // 0-weights => OOB rows stay 0
    }

    const float4 z = make_float4(0.f, 0.f, 0.f, 0.f);

    for (int ch = 0; ch < CGRP; ch += CSUB) {
        const float* sp = src + ((size_t)n * CC + cb + ch) * PLANE;

        // ---- load 36x128 region x 4 channels (permuted layout, zero-padded rows) ----
        for (int idx = t; idx < RROWS * WW; idx += NTH) {
            const int r  = idx >> 7;
            const int J  = idx & 127;
            const int gr = tr0 - HALO + r;
            float4 v = z;
            if (gr >= 0 && gr < HH) {
                const int o = gr * WW + J;
                v.x = sp[o];
                v.y = sp[PLANE + o];
                v.z = sp[2 * PLANE + o];
                v.w = sp[3 * PLANE + o];
            }
            bufA[r * RSTR4 + PERM(J)] = v;
        }
        __syncthreads();

        // ---- 10 fused steps, valid rows shrink top/bottom by 1 per step ----
        float4* pin  = bufA;
        float4* pout = bufB;
        for (int st = 0; st < NSTEPS; ++st) {
            const int lo = st + 1;
            const int hi = 34 - st;
            if (row >= lo && row <= hi) {
                float4 acc[8];
#pragma unroll
                for (int i = 0; i < 8; ++i) acc[i] = z;
#pragma unroll
                for (int di = 0; di < 3; ++di) {
                    const float4* rp = pin + (row - 1 + di) * RSTR4;
                    float4 x[10];
                    // left cell 8s-1 = 8(s-1)+7 -> perm 112 + (s-1); col -1 of image = 0
                    x[0] = (s > 0) ? rp[112 + s - 1] : z;
#pragma unroll
                    for (int k = 0; k < 8; ++k)          // cells 8s+k -> perm k*16 + s
                        x[k + 1] = rp[k * 16 + s];
                    // right cell 8s+8 = 8(s+1) -> perm s+1; col 128 of image = 0
                    x[9] = (s < 15) ? rp[s + 1] : z;
#pragma unroll
                    for (int dj = 0; dj < 3; ++dj) {
                        const int kk = di * 3 + dj;
#pragma unroll
                        for (int i = 0; i < 8; ++i)
                            acc[i] = fma4(x[i + dj], wt[kk][i], acc[i]);
                    }
                }
                float4* op = pout + row * RSTR4;
#pragma unroll
                for (int i = 0; i < 8; ++i)
                    op[i * 16 + s] = acc[i];
            }
            __syncthreads();
            float4* tmp = pin; pin = pout; pout = tmp;
        }

        // ---- store 16x128 core x 4 channels ----
        float* dp = dst + ((size_t)n * CC + cb + ch) * PLANE;
        for (int idx = t; idx < TH * WW; idx += NTH) {
            const int r = idx >> 7;
            const int J = idx & 127;
            const float4 v = pin[(r + HALO) * RSTR4 + PERM(J)];
            const int o = (tr0 + r) * WW + J;
            dp[o] = v.x;
            dp[PLANE + o] = v.y;
            dp[2 * PLANE + o] = v.z;
            dp[3 * PLANE + o] = v.w;
        }
        __syncthreads();   // protect bufA before next chunk's load
    }
}

extern "C" void kernel_launch(void* const* d_in, const int* in_sizes, int n_in,
                              void* d_out, int out_size, void* d_ws, size_t ws_size,
                              hipStream_t stream) {
    const float* input  = (const float*)d_in[0];
    const float* weight = (const float*)d_in[1];
    float* out = (float*)d_out;
    float* nw  = (float*)d_ws;   // 4.72 MB normalized weights

    mp_norm_kernel<<<128, 256, 0, stream>>>(weight, nw);
    mp_fused_kernel<<<256, NTH, 0, stream>>>(input, out, nw);
}

// Round 4
// 676.221 us; speedup vs baseline: 1.0641x; 1.0641x over previous
//
#include <hip/hip_runtime.h>

// MessagePassing: 10 iterations of 3x3 per-pixel-weighted smoothing, fully fused.
//   input [8,64,128,128] f32, weight [8,9,128,128] f32 -> out [8,64,128,128] f32
// R4 = R3 (full-width 128W x 16H tiles, halo 10, permuted conflict-free LDS,
// 256 blocks) + VECTORIZED per-thread weight preload (2x float4 per tap).
// R3's 862 MB FETCH_SIZE came from 72 scalar 4B weight loads/thread with 32B
// lane stride (8x line re-read thrashing L1/L2); dense dwordx4 kills it.

#define NB    8
#define CC    64
#define HH    128
#define WW    128
#define TAPS  9
#define PLANE (HH * WW)

#define TH     16            // output tile rows
#define HALO   10
#define RROWS  36            // TH + 2*HALO
#define RSTR4  129           // LDS row stride in float4 (odd -> +1 bank-group/row)
#define NTH    576           // 36 rows * 16 strips, 9 waves
#define NSTEPS 10
#define CGRP   16            // channels per block
#define CSUB   4             // channels per chunk (float4)

#define PERM(J) ((((J) & 7) << 4) | ((J) >> 3))   // bijective on 0..127

__device__ __forceinline__ float4 fma4(const float4 a, const float s, const float4 c) {
    return make_float4(fmaf(a.x, s, c.x), fmaf(a.y, s, c.y),
                       fmaf(a.z, s, c.z), fmaf(a.w, s, c.w));
}

__global__ __launch_bounds__(256) void mp_norm_kernel(const float* __restrict__ w,
                                                      float* __restrict__ nw) {
    int tid = blockIdx.x * 256 + threadIdx.x;       // 32768 threads
    int wg = tid & 31;
    int h  = (tid >> 5) & 127;
    int n  = tid >> 12;
    int base = n * TAPS * PLANE + h * WW + wg * 4;
    float4 t[TAPS];
    float sx = 1e-5f, sy = 1e-5f, sz = 1e-5f, sw = 1e-5f;
#pragma unroll
    for (int k = 0; k < TAPS; ++k) {
        t[k] = *reinterpret_cast<const float4*>(w + base + k * PLANE);
        sx += t[k].x; sy += t[k].y; sz += t[k].z; sw += t[k].w;
    }
    float rx = 1.0f / sx, ry = 1.0f / sy, rz = 1.0f / sz, rw = 1.0f / sw;
#pragma unroll
    for (int k = 0; k < TAPS; ++k) {
        float4 o = make_float4(t[k].x * rx, t[k].y * ry, t[k].z * rz, t[k].w * rw);
        *reinterpret_cast<float4*>(nw + base + k * PLANE) = o;
    }
}

__global__ __launch_bounds__(NTH, 1) void mp_fused_kernel(const float* __restrict__ src,
                                                          float* __restrict__ dst,
                                                          const float* __restrict__ nw) {
    __shared__ float4 bufA[RROWS * RSTR4];   // 74,304 B
    __shared__ float4 bufB[RROWS * RSTR4];   // total 148,608 B

    const int bid = blockIdx.x;              // 256 blocks: n*32 + ht*4 + cg
    const int n   = bid >> 5;
    const int ht  = (bid >> 2) & 7;
    const int cg  = bid & 3;
    const int tr0 = ht * TH;
    const int cb  = cg * CGRP;

    const int t   = threadIdx.x;
    const int row = t >> 4;                  // 0..35 region row
    const int s   = t & 15;                  // strip: pixels 8s..8s+7

    // ---- per-thread weights: 8 px x 9 taps, loaded as dense float4 pairs ----
    float wt[TAPS][8];
    {
        const int gr   = tr0 - HALO + row;
        const bool rin = (gr >= 0 && gr < HH);
        const float* nwb = nw + (size_t)n * TAPS * PLANE + (rin ? gr * WW : 0) + s * 8;
#pragma unroll
        for (int k = 0; k < TAPS; ++k) {
            const float4 lo = *reinterpret_cast<const float4*>(nwb + k * PLANE);
            const float4 hi = *reinterpret_cast<const float4*>(nwb + k * PLANE + 4);
            wt[k][0] = rin ? lo.x : 0.f;
            wt[k][1] = rin ? lo.y : 0.f;
            wt[k][2] = rin ? lo.z : 0.f;
            wt[k][3] = rin ? lo.w : 0.f;
            wt[k][4] = rin ? hi.x : 0.f;
            wt[k][5] = rin ? hi.y : 0.f;
            wt[k][6] = rin ? hi.z : 0.f;
            wt[k][7] = rin ? hi.w : 0.f;     // 0-weights => OOB rows stay 0
        }
    }

    const float4 z = make_float4(0.f, 0.f, 0.f, 0.f);

    for (int ch = 0; ch < CGRP; ch += CSUB) {
        const float* sp = src + ((size_t)n * CC + cb + ch) * PLANE;

        // ---- load 36x128 region x 4 channels (permuted layout, zero-padded rows) ----
        for (int idx = t; idx < RROWS * WW; idx += NTH) {
            const int r  = idx >> 7;
            const int J  = idx & 127;
            const int gr = tr0 - HALO + r;
            float4 v = z;
            if (gr >= 0 && gr < HH) {
                const int o = gr * WW + J;
                v.x = sp[o];
                v.y = sp[PLANE + o];
                v.z = sp[2 * PLANE + o];
                v.w = sp[3 * PLANE + o];
            }
            bufA[r * RSTR4 + PERM(J)] = v;
        }
        __syncthreads();

        // ---- 10 fused steps, valid rows shrink top/bottom by 1 per step ----
        float4* pin  = bufA;
        float4* pout = bufB;
        for (int st = 0; st < NSTEPS; ++st) {
            const int lo = st + 1;
            const int hi = 34 - st;
            if (row >= lo && row <= hi) {
                float4 acc[8];
#pragma unroll
                for (int i = 0; i < 8; ++i) acc[i] = z;
#pragma unroll
                for (int di = 0; di < 3; ++di) {
                    const float4* rp = pin + (row - 1 + di) * RSTR4;
                    float4 x[10];
                    // left cell 8s-1 = 8(s-1)+7 -> perm 112 + (s-1); col -1 of image = 0
                    x[0] = (s > 0) ? rp[112 + s - 1] : z;
#pragma unroll
                    for (int k = 0; k < 8; ++k)          // cells 8s+k -> perm k*16 + s
                        x[k + 1] = rp[k * 16 + s];
                    // right cell 8s+8 = 8(s+1) -> perm s+1; col 128 of image = 0
                    x[9] = (s < 15) ? rp[s + 1] : z;
#pragma unroll
                    for (int dj = 0; dj < 3; ++dj) {
                        const int kk = di * 3 + dj;
#pragma unroll
                        for (int i = 0; i < 8; ++i)
                            acc[i] = fma4(x[i + dj], wt[kk][i], acc[i]);
                    }
                }
                float4* op = pout + row * RSTR4;
#pragma unroll
                for (int i = 0; i < 8; ++i)
                    op[i * 16 + s] = acc[i];
            }
            __syncthreads();
            float4* tmp = pin; pin = pout; pout = tmp;
        }

        // ---- store 16x128 core x 4 channels ----
        float* dp = dst + ((size_t)n * CC + cb + ch) * PLANE;
        for (int idx = t; idx < TH * WW; idx += NTH) {
            const int r = idx >> 7;
            const int J = idx & 127;
            const float4 v = pin[(r + HALO) * RSTR4 + PERM(J)];
            const int o = (tr0 + r) * WW + J;
            dp[o] = v.x;
            dp[PLANE + o] = v.y;
            dp[2 * PLANE + o] = v.z;
            dp[3 * PLANE + o] = v.w;
        }
        __syncthreads();   // protect bufA before next chunk's load
    }
}

extern "C" void kernel_launch(void* const* d_in, const int* in_sizes, int n_in,
                              void* d_out, int out_size, void* d_ws, size_t ws_size,
                              hipStream_t stream) {
    const float* input  = (const float*)d_in[0];
    const float* weight = (const float*)d_in[1];
    float* out = (float*)d_out;
    float* nw  = (float*)d_ws;   // 4.72 MB normalized weights

    mp_norm_kernel<<<128, 256, 0, stream>>>(weight, nw);
    mp_fused_kernel<<<256, NTH, 0, stream>>>(input, out, nw);
}

// Round 5
// 674.137 us; speedup vs baseline: 1.0674x; 1.0031x over previous
//
#include <hip/hip_runtime.h>

// MessagePassing: 10 iterations of 3x3 per-pixel-weighted smoothing, fully fused.
//   input [8,64,128,128] f32, weight [8,9,128,128] f32 -> out [8,64,128,128] f32
// R5 = R4 (full-width 128W x 16H tiles, halo 10, permuted conflict-free LDS,
// 256 blocks, vectorized weight preload) + two fixes:
//  1. asm-pin the 72 per-thread weights so the compiler cannot sink the weight
//     loads into the step loop (R3/R4: VGPR=84 proved it rematerialized them
//     from global EVERY step -> 816 MB FETCH, latency-bound, VALUBusy 3.7%).
//  2. XCD swizzle: n = bid&7, so one image's 32 blocks share one XCD's L2
//     (vertical neighbors share 20/36 halo rows).

#define NB    8
#define CC    64
#define HH    128
#define WW    128
#define TAPS  9
#define PLANE (HH * WW)

#define TH     16            // output tile rows
#define HALO   10
#define RROWS  36            // TH + 2*HALO
#define RSTR4  129           // LDS row stride in float4 (odd -> +1 bank-group/row)
#define NTH    576           // 36 rows * 16 strips, 9 waves
#define NSTEPS 10
#define CGRP   16            // channels per block
#define CSUB   4             // channels per chunk (float4)

#define PERM(J) ((((J) & 7) << 4) | ((J) >> 3))   // bijective on 0..127

__device__ __forceinline__ float4 fma4(const float4 a, const float s, const float4 c) {
    return make_float4(fmaf(a.x, s, c.x), fmaf(a.y, s, c.y),
                       fmaf(a.z, s, c.z), fmaf(a.w, s, c.w));
}

__global__ __launch_bounds__(256) void mp_norm_kernel(const float* __restrict__ w,
                                                      float* __restrict__ nw) {
    int tid = blockIdx.x * 256 + threadIdx.x;       // 32768 threads
    int wg = tid & 31;
    int h  = (tid >> 5) & 127;
    int n  = tid >> 12;
    int base = n * TAPS * PLANE + h * WW + wg * 4;
    float4 t[TAPS];
    float sx = 1e-5f, sy = 1e-5f, sz = 1e-5f, sw = 1e-5f;
#pragma unroll
    for (int k = 0; k < TAPS; ++k) {
        t[k] = *reinterpret_cast<const float4*>(w + base + k * PLANE);
        sx += t[k].x; sy += t[k].y; sz += t[k].z; sw += t[k].w;
    }
    float rx = 1.0f / sx, ry = 1.0f / sy, rz = 1.0f / sz, rw = 1.0f / sw;
#pragma unroll
    for (int k = 0; k < TAPS; ++k) {
        float4 o = make_float4(t[k].x * rx, t[k].y * ry, t[k].z * rz, t[k].w * rw);
        *reinterpret_cast<float4*>(nw + base + k * PLANE) = o;
    }
}

__global__ __launch_bounds__(NTH, 1) void mp_fused_kernel(const float* __restrict__ src,
                                                          float* __restrict__ dst,
                                                          const float* __restrict__ nw) {
    __shared__ float4 bufA[RROWS * RSTR4];   // 74,304 B
    __shared__ float4 bufB[RROWS * RSTR4];   // total 148,608 B

    const int bid = blockIdx.x;              // 256 blocks
    const int n   = bid & 7;                 // XCD = bid % 8 -> one image per XCD
    const int ht  = (bid >> 3) & 7;
    const int cg  = bid >> 6;
    const int tr0 = ht * TH;
    const int cb  = cg * CGRP;

    const int t   = threadIdx.x;
    const int row = t >> 4;                  // 0..35 region row
    const int s   = t & 15;                  // strip: pixels 8s..8s+7

    // ---- per-thread weights: 8 px x 9 taps, dense float4 loads, then PINNED ----
    float wt[TAPS][8];
    {
        const int gr   = tr0 - HALO + row;
        const bool rin = (gr >= 0 && gr < HH);
        const float* nwb = nw + (size_t)n * TAPS * PLANE + (rin ? gr * WW : 0) + s * 8;
#pragma unroll
        for (int k = 0; k < TAPS; ++k) {
            const float4 lo = *reinterpret_cast<const float4*>(nwb + k * PLANE);
            const float4 hi = *reinterpret_cast<const float4*>(nwb + k * PLANE + 4);
            wt[k][0] = rin ? lo.x : 0.f;
            wt[k][1] = rin ? lo.y : 0.f;
            wt[k][2] = rin ? lo.z : 0.f;
            wt[k][3] = rin ? lo.w : 0.f;
            wt[k][4] = rin ? hi.x : 0.f;
            wt[k][5] = rin ? hi.y : 0.f;
            wt[k][6] = rin ? hi.z : 0.f;
            wt[k][7] = rin ? hi.w : 0.f;     // 0-weights => OOB rows stay 0
        }
    }
    // Pin: forces the weights to live in VGPRs for the whole kernel; the
    // compiler can no longer re-load them from global inside the step loop.
#pragma unroll
    for (int k = 0; k < TAPS; ++k)
#pragma unroll
        for (int i = 0; i < 8; ++i)
            asm volatile("" : "+v"(wt[k][i]));

    const float4 z = make_float4(0.f, 0.f, 0.f, 0.f);

    for (int ch = 0; ch < CGRP; ch += CSUB) {
        const float* sp = src + ((size_t)n * CC + cb + ch) * PLANE;

        // ---- load 36x128 region x 4 channels (permuted layout, zero-padded rows) ----
        for (int idx = t; idx < RROWS * WW; idx += NTH) {
            const int r  = idx >> 7;
            const int J  = idx & 127;
            const int gr = tr0 - HALO + r;
            float4 v = z;
            if (gr >= 0 && gr < HH) {
                const int o = gr * WW + J;
                v.x = sp[o];
                v.y = sp[PLANE + o];
                v.z = sp[2 * PLANE + o];
                v.w = sp[3 * PLANE + o];
            }
            bufA[r * RSTR4 + PERM(J)] = v;
        }
        __syncthreads();

        // ---- 10 fused steps, valid rows shrink top/bottom by 1 per step ----
        float4* pin  = bufA;
        float4* pout = bufB;
        for (int st = 0; st < NSTEPS; ++st) {
            const int lo = st + 1;
            const int hi = 34 - st;
            if (row >= lo && row <= hi) {
                float4 acc[8];
#pragma unroll
                for (int i = 0; i < 8; ++i) acc[i] = z;
#pragma unroll
                for (int di = 0; di < 3; ++di) {
                    const float4* rp = pin + (row - 1 + di) * RSTR4;
                    float4 x[10];
                    // left cell 8s-1 = 8(s-1)+7 -> perm 112 + (s-1); col -1 of image = 0
                    x[0] = (s > 0) ? rp[112 + s - 1] : z;
#pragma unroll
                    for (int k = 0; k < 8; ++k)          // cells 8s+k -> perm k*16 + s
                        x[k + 1] = rp[k * 16 + s];
                    // right cell 8s+8 = 8(s+1) -> perm s+1; col 128 of image = 0
                    x[9] = (s < 15) ? rp[s + 1] : z;
#pragma unroll
                    for (int dj = 0; dj < 3; ++dj) {
                        const int kk = di * 3 + dj;
#pragma unroll
                        for (int i = 0; i < 8; ++i)
                            acc[i] = fma4(x[i + dj], wt[kk][i], acc[i]);
                    }
                }
                float4* op = pout + row * RSTR4;
#pragma unroll
                for (int i = 0; i < 8; ++i)
                    op[i * 16 + s] = acc[i];
            }
            __syncthreads();
            float4* tmp = pin; pin = pout; pout = tmp;
        }

        // ---- store 16x128 core x 4 channels ----
        float* dp = dst + ((size_t)n * CC + cb + ch) * PLANE;
        for (int idx = t; idx < TH * WW; idx += NTH) {
            const int r = idx >> 7;
            const int J = idx & 127;
            const float4 v = pin[(r + HALO) * RSTR4 + PERM(J)];
            const int o = (tr0 + r) * WW + J;
            dp[o] = v.x;
            dp[PLANE + o] = v.y;
            dp[2 * PLANE + o] = v.z;
            dp[3 * PLANE + o] = v.w;
        }
        __syncthreads();   // protect bufA before next chunk's load
    }
}

extern "C" void kernel_launch(void* const* d_in, const int* in_sizes, int n_in,
                              void* d_out, int out_size, void* d_ws, size_t ws_size,
                              hipStream_t stream) {
    const float* input  = (const float*)d_in[0];
    const float* weight = (const float*)d_in[1];
    float* out = (float*)d_out;
    float* nw  = (float*)d_ws;   // 4.72 MB normalized weights

    mp_norm_kernel<<<128, 256, 0, stream>>>(weight, nw);
    mp_fused_kernel<<<256, NTH, 0, stream>>>(input, out, nw);
}

// Round 6
// 199.737 us; speedup vs baseline: 3.6026x; 3.3751x over previous
//
#include <hip/hip_runtime.h>

// MessagePassing: 10 iterations of 3x3 per-pixel-weighted smoothing.
//   input [8,64,128,128] f32, weight [8,9,128,128] f32 -> out [8,64,128,128] f32
// R6: TWO 5-step fused kernels (halo 5). Full-width 128W x 16H core, 26-row
// region, 4 px/thread -> 36 weight regs (R2-proven VGPR-resident; R3-R5's 72
// regs/thread got spilled and re-read every step = 800 MB L2 fill, 3.8% VALU).
// Permuted LDS layout (J -> (J&3)*32 | J>>2, row stride 129) gives exactly
// 8 lanes/bank-group on every ds_read_b128/write = conflict-free.

#define NB    8
#define CC    64
#define HH    128
#define WW    128
#define TAPS  9
#define PLANE (HH * WW)

#define CORE   16            // output tile rows per kernel
#define HALO5  5
#define RROWS  26            // CORE + 2*HALO5
#define RSTR4  129           // LDS row stride in float4 (odd -> +1 bank-group/row)
#define NTH    832           // 26 rows * 32 strips, 13 waves
#define NSTEP  5
#define CGRP   16            // channels per block
#define CSUB   4             // channels per chunk (float4 over channels)

#define PERM4(J) ((((J) & 3) << 5) | ((J) >> 2))   // bijective on 0..127

#define NWFLOATS (NB * TAPS * PLANE)               // 1,179,648 floats (4.7 MB)

__device__ __forceinline__ float4 fma4(const float4 a, const float s, const float4 c) {
    return make_float4(fmaf(a.x, s, c.x), fmaf(a.y, s, c.y),
                       fmaf(a.z, s, c.z), fmaf(a.w, s, c.w));
}

__global__ __launch_bounds__(256) void mp_norm_kernel(const float* __restrict__ w,
                                                      float* __restrict__ nw) {
    int tid = blockIdx.x * 256 + threadIdx.x;       // 32768 threads
    int wg = tid & 31;
    int h  = (tid >> 5) & 127;
    int n  = tid >> 12;
    int base = n * TAPS * PLANE + h * WW + wg * 4;
    float4 t[TAPS];
    float sx = 1e-5f, sy = 1e-5f, sz = 1e-5f, sw = 1e-5f;
#pragma unroll
    for (int k = 0; k < TAPS; ++k) {
        t[k] = *reinterpret_cast<const float4*>(w + base + k * PLANE);
        sx += t[k].x; sy += t[k].y; sz += t[k].z; sw += t[k].w;
    }
    float rx = 1.0f / sx, ry = 1.0f / sy, rz = 1.0f / sz, rw = 1.0f / sw;
#pragma unroll
    for (int k = 0; k < TAPS; ++k) {
        float4 o = make_float4(t[k].x * rx, t[k].y * ry, t[k].z * rz, t[k].w * rw);
        *reinterpret_cast<float4*>(nw + base + k * PLANE) = o;
    }
}

__global__ __launch_bounds__(NTH, 1) void mp_fused5_kernel(const float* __restrict__ src,
                                                           float* __restrict__ dst,
                                                           const float* __restrict__ nw) {
    __shared__ float4 bufA[RROWS * RSTR4];   // 53,664 B
    __shared__ float4 bufB[RROWS * RSTR4];   // total 107,328 B

    const int bid = blockIdx.x;              // 256 blocks
    const int n   = bid & 7;                 // image -> XCD affinity
    const int ht  = (bid >> 3) & 7;
    const int cg  = bid >> 6;
    const int tr0 = ht * CORE;
    const int cb  = cg * CGRP;

    const int t   = threadIdx.x;
    const int row = t >> 5;                  // 0..25 region row
    const int s   = t & 31;                  // strip: pixels 4s..4s+3

    // ---- per-thread weights: 4 px x 9 taps = 36 regs (dense float4 loads) ----
    float4 wt[TAPS];                         // wt[k] = taps k for px 4s..4s+3
    {
        const int gr   = tr0 - HALO5 + row;
        const bool rin = (gr >= 0 && gr < HH);
        const float* nwb = nw + (size_t)n * TAPS * PLANE + (rin ? gr * WW : 0) + s * 4;
#pragma unroll
        for (int k = 0; k < TAPS; ++k) {
            const float4 v = *reinterpret_cast<const float4*>(nwb + k * PLANE);
            wt[k] = rin ? v : make_float4(0.f, 0.f, 0.f, 0.f);  // OOB rows -> 0
        }
    }

    const float4 z = make_float4(0.f, 0.f, 0.f, 0.f);

    for (int ch = 0; ch < CGRP; ch += CSUB) {
        const float* sp = src + ((size_t)n * CC + cb + ch) * PLANE;

        // ---- load 26x128 region x 4 channels (permuted layout, zero-pad rows) ----
        for (int idx = t; idx < RROWS * WW; idx += NTH) {      // exactly 4 iters
            const int r  = idx >> 7;
            const int J  = idx & 127;
            const int gr = tr0 - HALO5 + r;
            float4 v = z;
            if (gr >= 0 && gr < HH) {
                const int o = gr * WW + J;
                v.x = sp[o];
                v.y = sp[PLANE + o];
                v.z = sp[2 * PLANE + o];
                v.w = sp[3 * PLANE + o];
            }
            bufA[r * RSTR4 + PERM4(J)] = v;
        }
        __syncthreads();

        // ---- 5 fused steps, valid rows shrink top/bottom by 1 per step ----
        float4* pin  = bufA;
        float4* pout = bufB;
        for (int st = 0; st < NSTEP; ++st) {
            const int lo = st + 1;
            const int hi = 24 - st;
            if (row >= lo && row <= hi) {
                float4 acc0 = z, acc1 = z, acc2 = z, acc3 = z;
#pragma unroll
                for (int di = 0; di < 3; ++di) {
                    const float4* rp = pin + (row - 1 + di) * RSTR4;
                    // cells at columns 4s-1 .. 4s+4 (permuted addresses)
                    float4 xv[6];
                    xv[0] = (s > 0) ? rp[96 + s - 1] : z;   // col 4s-1
                    xv[1] = rp[s];                          // col 4s
                    xv[2] = rp[32 + s];                     // col 4s+1
                    xv[3] = rp[64 + s];                     // col 4s+2
                    xv[4] = rp[96 + s];                     // col 4s+3
                    xv[5] = (s < 31) ? rp[s + 1] : z;       // col 4s+4
#pragma unroll
                    for (int dj = 0; dj < 3; ++dj) {
                        const int k = di * 3 + dj;
                        acc0 = fma4(xv[0 + dj], wt[k].x, acc0);
                        acc1 = fma4(xv[1 + dj], wt[k].y, acc1);
                        acc2 = fma4(xv[2 + dj], wt[k].z, acc2);
                        acc3 = fma4(xv[3 + dj], wt[k].w, acc3);
                    }
                }
                float4* op = pout + row * RSTR4;
                op[s]      = acc0;
                op[32 + s] = acc1;
                op[64 + s] = acc2;
                op[96 + s] = acc3;
            }
            __syncthreads();
            float4* tmp = pin; pin = pout; pout = tmp;
        }

        // ---- store 16x128 core x 4 channels ----
        float* dp = dst + ((size_t)n * CC + cb + ch) * PLANE;
        for (int idx = t; idx < CORE * WW; idx += NTH) {
            const int r = idx >> 7;
            const int J = idx & 127;
            const float4 v = pin[(r + HALO5) * RSTR4 + PERM4(J)];
            const int o = (tr0 + r) * WW + J;
            dp[o] = v.x;
            dp[PLANE + o] = v.y;
            dp[2 * PLANE + o] = v.z;
            dp[3 * PLANE + o] = v.w;
        }
        __syncthreads();   // protect bufA before next chunk's load
    }
}

extern "C" void kernel_launch(void* const* d_in, const int* in_sizes, int n_in,
                              void* d_out, int out_size, void* d_ws, size_t ws_size,
                              hipStream_t stream) {
    const float* input  = (const float*)d_in[0];
    const float* weight = (const float*)d_in[1];
    float* out = (float*)d_out;
    float* nw  = (float*)d_ws;               // 4.72 MB normalized weights
    float* B0  = nw + NWFLOATS;              // 33.5 MB intermediate (steps 1-5)

    mp_norm_kernel<<<128, 256, 0, stream>>>(weight, nw);
    mp_fused5_kernel<<<256, NTH, 0, stream>>>(input, B0, nw);   // steps 1..5
    mp_fused5_kernel<<<256, NTH, 0, stream>>>(B0, out, nw);     // steps 6..10
}